// Round 12
// baseline (81.381 us; speedup 1.0000x reference)
//
#include <hip/hip_runtime.h>

#define IMG   128
#define KF    4
#define NF    800
#define NV    2000
#define NB    2
#define EPSF  1e-8f
#define BLURF 0.01f
// rect-edge cull: dist>0.1015 => (w/len)^2 > 0.0103 with w<0
#define CULL_D2 0.0103f
#define HEXT    0.0547f   // tile half-extent (7/128) + margin
#define AREA_SLIVER 0.01f // |area| below this: no z-skip (float-bound safety)
#define ZSLACK  0.05f     // z-bound slack >> max float error (~4e-3)

typedef unsigned long long u64;
#define INVK ((((u64)0x7f800000u) << 32) | 0xffffffffu)   // z=+inf, idx=-1

// Match numpy: no FMA contraction anywhere on the exact paths.
#pragma clang fp contract(off)

// ---- fast almost-IEEE division (p1 selection path only) ----
// y = rcp refined by 2 Newton steps, then per-divide Markstein residual
// correction: differs from IEEE RN division only when the exact quotient is
// within ~2^-47 (rel) of a rounding boundary (P ~ 1e-7/op). p2 recomputes all
// OUTPUT values with true IEEE divides; only top-k selection carries the
// negligible risk. Field-proven: r1-r11 all passed.
__device__ __forceinline__ float rcp2(float d) {
    float y = __builtin_amdgcn_rcpf(d);
    float e = __builtin_fmaf(-d, y, 1.0f);
    y = __builtin_fmaf(y, e, y);
    e = __builtin_fmaf(-d, y, 1.0f);
    y = __builtin_fmaf(y, e, y);
    return y;
}
__device__ __forceinline__ float fdivr(float n, float d, float y) {
    float q0 = n * y;
    float r  = __builtin_fmaf(-d, q0, n);
    return __builtin_fmaf(r, y, q0);
}

// exact-IEEE version (p2 epilogue)
__device__ __forceinline__ float seg_d2(float pax, float pay, float abx, float aby) {
#pragma clang fp contract(off)
    float dd = (abx * abx + aby * aby) + EPSF;
    float t  = (pax * abx + pay * aby) / dd;   // true IEEE divide
    t = fminf(fmaxf(t, 0.0f), 1.0f);
    float dx = pax - t * abx;
    float dy = pay - t * aby;
    return dx * dx + dy * dy;
}

// fast version with pre-staged reciprocal seed y == rcp2((ab.ab)+EPS)
__device__ __forceinline__ float seg_d2y(float pax, float pay, float abx, float aby, float y) {
#pragma clang fp contract(off)
    float dd = (abx * abx + aby * aby) + EPSF;   // ref op order
    float n  = pax * abx + pay * aby;
    float t  = fdivr(n, dd, y);
    t = fminf(fmaxf(t, 0.0f), 1.0f);
    float dx = pax - t * abx;
    float dy = pay - t * aby;
    return dx * dx + dy * dy;
}

__device__ __forceinline__ void ins4(u64& s0, u64& s1, u64& s2, u64& s3, u64 k) {
    bool c0 = k < s0, c1 = k < s1, c2 = k < s2, c3 = k < s3;
    s3 = c2 ? s2 : (c3 ? k : s3);
    s2 = c1 ? s1 : (c2 ? k : s2);
    s1 = c0 ? s0 : (c1 ? k : s1);
    s0 = c0 ? k  : s0;
}

// one survivor record -> candidate key (straight-line, no s3 dependence).
// Slow seg-distance path runs ONLY if some lane is outside AND within the
// provable line-distance blur band (w^2*yl <= CULL_D2). The filter is
// s3-independent (pure data) so cross-iteration ILP is preserved; its
// reject direction is exact (line-dist lower-bounds seg-dist, yl under-
// estimates 1/l, CULL_D2 carries 3% guard) -- field-validated in r4.
__device__ __forceinline__ u64 eval_rec(const float4* fd, float px, float py) {
#pragma clang fp contract(off)
    float4 r0 = fd[0];
    float4 r1 = fd[1];
    float4 r2 = fd[2];
    float4 r3 = fd[3];
    float a0x = r0.x, a0y = r0.y, a1x = r0.z, a1y = r0.w;
    float a2x = r1.x, a2y = r1.y, z0 = r1.z, z1 = r1.w;
    float z2 = r2.x, denom = r2.y, yd = r2.z;
    unsigned fi = __float_as_uint(r2.w);
    float ylA = r3.x, ylB = r3.y, ylC = r3.z;

    float e0x = a2x - a1x, e0y = a2y - a1y;   // a1->a2
    float e1x = a0x - a2x, e1y = a0y - a2y;   // a2->a0
    float e2x = a1x - a0x, e2y = a1y - a0y;   // a0->a1
    float p0x = px - a0x, p0y = py - a0y;
    float p1x = px - a1x, p1y = py - a1y;
    float p2x = px - a2x, p2y = py - a2y;
    float w0 = p1x * e0y - p1y * e0x;
    float w1 = p2x * e1y - p2y * e1x;
    float w2 = p0x * e2y - p0y * e2x;
    float b0 = fdivr(w0, denom, yd);
    float b1 = fdivr(w1, denom, yd);
    float b2 = fdivr(w2, denom, yd);
    float zpix = (b0 * z0 + b1 * z1) + b2 * z2;               // numpy order
    bool inside = fminf(b0, fminf(b1, b2)) >= 0.0f;           // no NaNs possible

    // certain-reject: all three line-distance lower bounds exceed the blur
    // radius => ref's dmin > BLURF => this lane can only qualify if inside.
    bool farA = (w2 * w2) * ylA > CULL_D2;    // seg a0->a1
    bool farB = (w0 * w0) * ylB > CULL_D2;    // seg a1->a2
    bool farC = (w1 * w1) * ylC > CULL_D2;    // seg a2->a0
    bool need = (!inside) & !(farA & farB & farC);

    bool valid;
    if (!__any(need)) {
        valid = inside & (zpix > EPSF);       // outside lanes: proven invalid
    } else {
        float dA = seg_d2y(p0x, p0y, e2x, e2y, ylA);   // (p,a0,a1)
        float dB = seg_d2y(p1x, p1y, e0x, e0y, ylB);   // (p,a1,a2)
        float dC = seg_d2y(p2x, p2y, e1x, e1y, ylC);   // (p,a2,a0)
        float dmin = fminf(dA, fminf(dB, dC));
        valid = (inside | (dmin < BLURF)) & (zpix > EPSF);
    }
    return valid ? ((((u64)__float_as_uint(zpix)) << 32) | (u64)fi) : INVK;
}

// ---------------- kernel 1: per (tile, face-slice) partial top-4 ----------------
// Structure NOTE (measured r0-r11): the main loop stays straight-line with
// ALL top-4 gating at the BOTTOM (top-gates collapse cross-iteration ILP:
// r1/r3 +5%, r4 +37%). Fence-fusion 3.5x worse (r6); work-stealing 25% worse
// (r9, TLP halved); 2x unroll neutral (r10). r11: survivors BIN-ORDERED by a
// provable per-tile z lower bound; between bins (8x max) an exact break
// fires once every lane's 4th key beats the remaining bins' bound.
__global__ __launch_bounds__(256) void raster_p1(
    const float* __restrict__ verts,   // (B, V, 3)
    const int*   __restrict__ faces,   // (F, 3)
    u64* __restrict__ ws,              // [512*S][4][64] partial keys
    int sh)                            // log2(slices)
{
#pragma clang fp contract(off)
    extern __shared__ __align__(16) float sFD[];   // [chunk][16] survivor records (64B)
    __shared__ u64 sK[2 * 4 * 64];     // merge rows (4 KB)
    __shared__ int sTot;
    __shared__ int binCnt[8];
    __shared__ int binCur[8];
    __shared__ int binStartS[9];

    const int S     = 1 << sh;
    const int chunk = NF >> sh;

    const int tid   = threadIdx.x;
    const int blk   = blockIdx.x;
    const int tile  = blk >> sh;
    const int slice = blk & (S - 1);
    const int b     = tile >> 8;
    const int trow  = (tile & 255) >> 4;
    const int tcol  = tile & 15;
    const float* vb = verts + b * NV * 3;
    const int fbase = slice * chunk;

    if (tid == 0) sTot = 0;
    if (tid < 8) binCnt[tid] = 0;

    // tile geometry (block-uniform)
    const float txmax = 1.0f - (2.0f * ((float)(tcol * 8)     + 0.5f)) / 128.0f;
    const float txmin = 1.0f - (2.0f * ((float)(tcol * 8 + 7) + 0.5f)) / 128.0f;
    const float tymax = 1.0f - (2.0f * ((float)(trow * 8)     + 0.5f)) / 128.0f;
    const float tymin = 1.0f - (2.0f * ((float)(trow * 8 + 7) + 0.5f)) / 128.0f;
    const float cx = 0.5f * (txmin + txmax);
    const float cy = 0.5f * (tymin + tymax);

    __syncthreads();   // counters visible

    if (chunk <= 256) {
        // ---- bin-ordered staging: each thread owns <=1 face, record lives in
        // registers across the count/prefix/scatter barriers (no recompute).
        bool surv = false;
        int bin = 0;
        float a0x=0, a0y=0, a1x=0, a1y=0, a2x=0, a2y=0, z0=0, z1=0, z2=0;
        float area=0, yd=0, ylA=0, ylB=0, ylC=0;
        int f = fbase + tid;
        if (tid < chunk) {
            int i0 = faces[3 * f + 0], i1 = faces[3 * f + 1], i2 = faces[3 * f + 2];
            a0x = vb[3 * i0]; a0y = vb[3 * i0 + 1]; z0 = vb[3 * i0 + 2];
            a1x = vb[3 * i1]; a1y = vb[3 * i1 + 1]; z1 = vb[3 * i1 + 2];
            a2x = vb[3 * i2]; a2y = vb[3 * i2 + 1]; z2 = vb[3 * i2 + 2];
            // numpy op order for area (exact-match)
            area = (a2x - a0x) * (a1y - a0y) - (a2y - a0y) * (a1x - a0x);
            surv = fabsf(area) > EPSF;
            float bxmin = fminf(a0x, fminf(a1x, a2x)) - 0.101f;
            float bxmax = fmaxf(a0x, fmaxf(a1x, a2x)) + 0.101f;
            float bymin = fminf(a0y, fminf(a1y, a2y)) - 0.101f;
            float bymax = fmaxf(a0y, fmaxf(a1y, a2y)) + 0.101f;
            surv &= !(bxmin > txmax || bxmax < txmin || bymin > tymax || bymax < tymin);
            // exact rect-vs-edge-line cull
            float s = (area >= 0.0f) ? 1.0f : -1.0f;
            float e0x = a2x - a1x, e0y = a2y - a1y;
            float e1x = a0x - a2x, e1y = a0y - a2y;
            float e2x = a1x - a0x, e2y = a1y - a0y;
            float w0 = s * ((cx - a1x) * e0y - (cy - a1y) * e0x) + HEXT * (fabsf(e0x) + fabsf(e0y));
            float w1 = s * ((cx - a2x) * e1y - (cy - a2y) * e1x) + HEXT * (fabsf(e1x) + fabsf(e1y));
            float w2 = s * ((cx - a0x) * e2y - (cy - a0y) * e2x) + HEXT * (fabsf(e2x) + fabsf(e2y));
            float l0 = e0x * e0x + e0y * e0y;
            float l1 = e1x * e1x + e1y * e1y;
            float l2 = e2x * e2x + e2y * e2y;
            surv &= !((w0 < 0.0f) & (w0 * w0 > CULL_D2 * l0));
            surv &= !((w1 < 0.0f) & (w1 * w1 > CULL_D2 * l1));
            surv &= !((w2 < 0.0f) & (w2 * w2 > CULL_D2 * l2));
            if (surv) {
                yd  = rcp2(area);          // survivor => denom == area
                ylA = rcp2(l2 + EPSF);     // seg a0->a1 (p0, e2) -> dA
                ylB = rcp2(l0 + EPSF);     // seg a1->a2 (p1, e0) -> dB
                ylC = rcp2(l1 + EPSF);     // seg a2->a0 (p2, e1) -> dC
                // z lower bound over the tile: z(x,y) is affine -> min at a
                // corner of the pixel-center rect. (*yd approx: covered by
                // ZSLACK; slivers excluded from skipping entirely.)
                float zmn = 1e30f;
                #pragma unroll
                for (int c = 0; c < 4; ++c) {
                    float X = (c & 1) ? txmax : txmin;
                    float Y = (c & 2) ? tymax : tymin;
                    float w0c = (X - a1x) * e0y - (Y - a1y) * e0x;
                    float w1c = (X - a2x) * e1y - (Y - a2y) * e1x;
                    float w2c = (X - a0x) * e2y - (Y - a0y) * e2x;
                    float zc = ((w0c * z0 + w1c * z1) + w2c * z2) * yd;
                    zmn = fminf(zmn, zc);
                }
                if (fabsf(area) < AREA_SLIVER) zmn = 0.0f;   // never skipped
                int bi = (int)floorf((zmn - 0.5f) * 4.0f);   // 8 bins of 0.25
                bin = bi < 0 ? 0 : (bi > 7 ? 7 : bi);
                atomicAdd(&binCnt[bin], 1);
            }
        }
        __syncthreads();
        if (tid == 0) {
            int run = 0;
            for (int bb = 0; bb < 8; ++bb) {
                binStartS[bb] = run;
                binCur[bb]    = run;
                run += binCnt[bb];
            }
            binStartS[8] = run;
        }
        __syncthreads();
        if (surv) {
            int pos = atomicAdd(&binCur[bin], 1);
            float4* fd = (float4*)&sFD[pos * 16];
            fd[0] = make_float4(a0x, a0y, a1x, a1y);
            fd[1] = make_float4(a2x, a2y, z0, z1);
            fd[2] = make_float4(z2, area, yd, __int_as_float(f));
            fd[3] = make_float4(ylA, ylB, ylC, 0.0f);
        }
        __syncthreads();
    } else {
        // fallback (sh<2): r8 staging, everything in bin 0, no z-skip
        for (int j = tid; j < chunk; j += 256) {
            int f = fbase + j;
            int i0 = faces[3 * f + 0], i1 = faces[3 * f + 1], i2 = faces[3 * f + 2];
            float a0x = vb[3 * i0], a0y = vb[3 * i0 + 1], z0 = vb[3 * i0 + 2];
            float a1x = vb[3 * i1], a1y = vb[3 * i1 + 1], z1 = vb[3 * i1 + 2];
            float a2x = vb[3 * i2], a2y = vb[3 * i2 + 1], z2 = vb[3 * i2 + 2];
            float area = (a2x - a0x) * (a1y - a0y) - (a2y - a0y) * (a1x - a0x);
            bool surv = fabsf(area) > EPSF;
            float bxmin = fminf(a0x, fminf(a1x, a2x)) - 0.101f;
            float bxmax = fmaxf(a0x, fmaxf(a1x, a2x)) + 0.101f;
            float bymin = fminf(a0y, fminf(a1y, a2y)) - 0.101f;
            float bymax = fmaxf(a0y, fmaxf(a1y, a2y)) + 0.101f;
            surv &= !(bxmin > txmax || bxmax < txmin || bymin > tymax || bymax < tymin);
            float s = (area >= 0.0f) ? 1.0f : -1.0f;
            float e0x = a2x - a1x, e0y = a2y - a1y;
            float e1x = a0x - a2x, e1y = a0y - a2y;
            float e2x = a1x - a0x, e2y = a1y - a0y;
            float w0 = s * ((cx - a1x) * e0y - (cy - a1y) * e0x) + HEXT * (fabsf(e0x) + fabsf(e0y));
            float w1 = s * ((cx - a2x) * e1y - (cy - a2y) * e1x) + HEXT * (fabsf(e1x) + fabsf(e1y));
            float w2 = s * ((cx - a0x) * e2y - (cy - a0y) * e2x) + HEXT * (fabsf(e2x) + fabsf(e2y));
            float l0 = e0x * e0x + e0y * e0y;
            float l1 = e1x * e1x + e1y * e1y;
            float l2 = e2x * e2x + e2y * e2y;
            surv &= !((w0 < 0.0f) & (w0 * w0 > CULL_D2 * l0));
            surv &= !((w1 < 0.0f) & (w1 * w1 > CULL_D2 * l1));
            surv &= !((w2 < 0.0f) & (w2 * w2 > CULL_D2 * l2));
            if (surv) {
                int pos = atomicAdd(&sTot, 1);
                float yd  = rcp2(area);
                float ylA = rcp2(l2 + EPSF);
                float ylB = rcp2(l0 + EPSF);
                float ylC = rcp2(l1 + EPSF);
                float4* fd = (float4*)&sFD[pos * 16];
                fd[0] = make_float4(a0x, a0y, a1x, a1y);
                fd[1] = make_float4(a2x, a2y, z0, z1);
                fd[2] = make_float4(z2, area, yd, __int_as_float(f));
                fd[3] = make_float4(ylA, ylB, ylC, 0.0f);
            }
        }
        __syncthreads();
        if (tid == 0) {
            binStartS[0] = 0;
            for (int bb = 1; bb <= 8; ++bb) binStartS[bb] = sTot;
        }
        __syncthreads();
    }

    const int wave = tid >> 6;
    const int lane = tid & 63;
    const int pr = lane >> 3, pc = lane & 7;          // 8x8 tile
    const int row = trow * 8 + pr, col = tcol * 8 + pc;
    const float px = 1.0f - (2.0f * ((float)col + 0.5f)) / 128.0f;
    const float py = 1.0f - (2.0f * ((float)row + 0.5f)) / 128.0f;

    // phase 1: bins in increasing-z order; within a bin the loop is the
    // r8-proven shape (straight-line, bottom gate). Break check reads s3 only
    // BETWEEN bins (<=8x) -- no per-iteration loop-carried dependency.
    u64 s0 = INVK, s1 = INVK, s2 = INVK, s3 = INVK;
    for (int bb = 0; bb < 8; ++bb) {
        if (bb > 0) {
            float bz = 0.5f + 0.25f * (float)bb - ZSLACK;
            u64 bk = ((u64)__float_as_uint(bz)) << 32;
            if (!__any(s3 > bk)) break;   // exact: future keys > bk >= all s3
        }
        const int jend = binStartS[bb + 1];
        for (int j = binStartS[bb] + wave; j < jend; j += 4) {
            u64 k = eval_rec((const float4*)&sFD[j * 16], px, py);
            if (__any(k < s3)) ins4(s0, s1, s2, s3, k);
        }
    }

    // cross-wave merge: 4 waves -> wave 0
    if (wave >= 2) {
        int r = wave - 2;
        sK[(r * 4 + 0) * 64 + lane] = s0;
        sK[(r * 4 + 1) * 64 + lane] = s1;
        sK[(r * 4 + 2) * 64 + lane] = s2;
        sK[(r * 4 + 3) * 64 + lane] = s3;
    }
    __syncthreads();
    if (wave < 2) {
        ins4(s0, s1, s2, s3, sK[(wave * 4 + 0) * 64 + lane]);
        ins4(s0, s1, s2, s3, sK[(wave * 4 + 1) * 64 + lane]);
        ins4(s0, s1, s2, s3, sK[(wave * 4 + 2) * 64 + lane]);
        ins4(s0, s1, s2, s3, sK[(wave * 4 + 3) * 64 + lane]);
    }
    __syncthreads();
    if (wave == 1) {
        sK[0 * 64 + lane] = s0;
        sK[1 * 64 + lane] = s1;
        sK[2 * 64 + lane] = s2;
        sK[3 * 64 + lane] = s3;
    }
    __syncthreads();
    if (wave == 0) {
        ins4(s0, s1, s2, s3, sK[0 * 64 + lane]);
        ins4(s0, s1, s2, s3, sK[1 * 64 + lane]);
        ins4(s0, s1, s2, s3, sK[2 * 64 + lane]);
        ins4(s0, s1, s2, s3, sK[3 * 64 + lane]);
        u64* wrow = ws + (size_t)blk * 256;
        wrow[0 * 64 + lane] = s0;
        wrow[1 * 64 + lane] = s1;
        wrow[2 * 64 + lane] = s2;
        wrow[3 * 64 + lane] = s3;
    }
}

// ---------------- kernel 2: merge slices + exact epilogue ----------------
__global__ __launch_bounds__(256) void raster_p2(
    const float* __restrict__ verts,
    const int*   __restrict__ faces,
    const u64* __restrict__ ws,
    int sh,
    float* __restrict__ out0, float* __restrict__ out1,
    float* __restrict__ out2, float* __restrict__ out3)
{
#pragma clang fp contract(off)
    __shared__ u64 sK[4 * 64];
    const int S    = 1 << sh;
    const int tid  = threadIdx.x;
    const int tile = blockIdx.x;
    const int b    = tile >> 8;
    const int trow = (tile & 255) >> 4;
    const int tcol = tile & 15;
    const float* vb = verts + b * NV * 3;

    if (tid < 64) {
        u64 s0 = INVK, s1 = INVK, s2 = INVK, s3 = INVK;
        const u64* base = ws + (size_t)tile * S * 256;
        for (int s = 0; s < S; ++s) {
            ins4(s0, s1, s2, s3, base[s * 256 + 0 * 64 + tid]);
            ins4(s0, s1, s2, s3, base[s * 256 + 1 * 64 + tid]);
            ins4(s0, s1, s2, s3, base[s * 256 + 2 * 64 + tid]);
            ins4(s0, s1, s2, s3, base[s * 256 + 3 * 64 + tid]);
        }
        sK[0 * 64 + tid] = s0;
        sK[1 * 64 + tid] = s1;
        sK[2 * 64 + tid] = s2;
        sK[3 * 64 + tid] = s3;
    }
    __syncthreads();

    int pix = tid >> 2, k = tid & 3;
    u64 key = sK[k * 64 + pix];
    int prow = pix >> 3, pcol = pix & 7;
    int grow = trow * 8 + prow, gcol = tcol * 8 + pcol;
    int p = (b * IMG + grow) * IMG + gcol;
    float qx = 1.0f - (2.0f * ((float)gcol + 0.5f)) / 128.0f;
    float qy = 1.0f - (2.0f * ((float)grow + 0.5f)) / 128.0f;
    float o0 = -1.0f, o1 = -1.0f, ob0 = -1.0f, ob1 = -1.0f, ob2 = -1.0f, o3 = -1.0f;
    if ((unsigned)(key >> 32) != 0x7f800000u) {
        int fi = (int)(unsigned)(key & 0xffffffffu);
        int i0 = faces[3 * fi + 0], i1 = faces[3 * fi + 1], i2 = faces[3 * fi + 2];
        float a0x = vb[3 * i0], a0y = vb[3 * i0 + 1], z0 = vb[3 * i0 + 2];
        float a1x = vb[3 * i1], a1y = vb[3 * i1 + 1], z1 = vb[3 * i1 + 2];
        float a2x = vb[3 * i2], a2y = vb[3 * i2 + 1], z2 = vb[3 * i2 + 2];
        float area = (a2x - a0x) * (a1y - a0y) - (a2y - a0y) * (a1x - a0x);
        float aab  = fabsf(area);
        float denom = (aab > EPSF) ? area : (area >= 0.0f ? EPSF : -EPSF);
        float e0x = a2x - a1x, e0y = a2y - a1y;
        float e1x = a0x - a2x, e1y = a0y - a2y;
        float e2x = a1x - a0x, e2y = a1y - a0y;
        float p0x = qx - a0x, p0y = qy - a0y;
        float p1x = qx - a1x, p1y = qy - a1y;
        float p2x = qx - a2x, p2y = qy - a2y;
        float w0 = p1x * e0y - p1y * e0x;
        float w1 = p2x * e1y - p2y * e1x;
        float w2 = p0x * e2y - p0y * e2x;
        float b0 = w0 / denom, b1 = w1 / denom, b2 = w2 / denom;   // true IEEE
        float zpix = (b0 * z0 + b1 * z1) + b2 * z2;
        bool inside = (b0 >= 0.0f) & (b1 >= 0.0f) & (b2 >= 0.0f);
        float dA = seg_d2(p0x, p0y, e2x, e2y);
        float dB = seg_d2(p1x, p1y, e0x, e0y);
        float dC = seg_d2(p2x, p2y, e1x, e1y);
        float dmin = fminf(dA, fminf(dB, dC));
        o0 = (float)fi;
        o1 = zpix;
        ob0 = b0; ob1 = b1; ob2 = b2;
        o3 = inside ? -dmin : dmin;
    }
    int o = p * KF + k;
    out0[o] = o0;
    out1[o] = o1;
    out2[o * 3 + 0] = ob0;
    out2[o * 3 + 1] = ob1;
    out2[o * 3 + 2] = ob2;
    out3[o] = o3;
}

extern "C" void kernel_launch(void* const* d_in, const int* in_sizes, int n_in,
                              void* d_out, int out_size, void* d_ws, size_t ws_size,
                              hipStream_t stream) {
    const float* verts = (const float*)d_in[0];
    const int*   faces = (const int*)d_in[1];
    float* out = (float*)d_out;
    const int n0 = NB * IMG * IMG * KF;   // 131072 per (B,H,W,K) output

    const size_t per_slice = 512ull * 256 * sizeof(u64);   // 1 MB
    // Measured: sh=3 worse (r1), 8-wave worse (r3), top-gated loops worse
    // (r1/r3/r4), fence-fused kernel 3.5x worse (r6), work-stealing 25% worse
    // (r9), 2x unroll neutral (r10). Best: sh=2 / bottom-gated loop + staged
    // seeds + compacted records (r8) + z-binned break (r11) + far-filter (r12).
    int sh;
    if      (ws_size >= 4 * per_slice) sh = 2;   // 4 slices
    else if (ws_size >= 2 * per_slice) sh = 1;   // 2 slices
    else                               sh = 0;   // 1 slice
    const int S = 1 << sh;
    const int chunk = NF >> sh;
    const size_t dyn = (size_t)chunk * 16 * sizeof(float);

    raster_p1<<<dim3(512 * S), dim3(256), dyn, stream>>>(verts, faces, (u64*)d_ws, sh);
    raster_p2<<<dim3(512), dim3(256), 0, stream>>>(verts, faces, (const u64*)d_ws, sh,
        out,                 // pix_to_face
        out + n0,            // zbuf
        out + 2 * n0,        // bary
        out + 5 * n0);       // dsign
}

// Round 13
// 79.591 us; speedup vs baseline: 1.0225x; 1.0225x over previous
//
#include <hip/hip_runtime.h>

#define IMG   128
#define KF    4
#define NF    800
#define NV    2000
#define NB    2
#define EPSF  1e-8f
#define BLURF 0.01f
// rect-edge cull: dist>0.1015 => (w/len)^2 > 0.0103 with w<0
#define CULL_D2 0.0103f
#define HEXT    0.0547f   // tile half-extent (7/128) + margin
#define AREA_SLIVER 0.01f // |area| below this: no z-skip (float-bound safety)
#define ZSLACK  0.05f     // z-bound slack >> max float error (~4e-3)

typedef unsigned long long u64;
#define INVK ((((u64)0x7f800000u) << 32) | 0xffffffffu)   // z=+inf, idx=-1

// Match numpy: no FMA contraction anywhere on the exact paths.
#pragma clang fp contract(off)

// ---- fast almost-IEEE division (p1 selection path only) ----
// y = rcp refined by 2 Newton steps, then per-divide Markstein residual
// correction: differs from IEEE RN division only when the exact quotient is
// within ~2^-47 (rel) of a rounding boundary (P ~ 1e-7/op). p2 recomputes all
// OUTPUT values with true IEEE divides; only top-k selection carries the
// negligible risk. Field-proven: r1-r12 all passed.
__device__ __forceinline__ float rcp2(float d) {
    float y = __builtin_amdgcn_rcpf(d);
    float e = __builtin_fmaf(-d, y, 1.0f);
    y = __builtin_fmaf(y, e, y);
    e = __builtin_fmaf(-d, y, 1.0f);
    y = __builtin_fmaf(y, e, y);
    return y;
}
__device__ __forceinline__ float fdivr(float n, float d, float y) {
    float q0 = n * y;
    float r  = __builtin_fmaf(-d, q0, n);
    return __builtin_fmaf(r, y, q0);
}

// exact-IEEE version (p2 epilogue)
__device__ __forceinline__ float seg_d2(float pax, float pay, float abx, float aby) {
#pragma clang fp contract(off)
    float dd = (abx * abx + aby * aby) + EPSF;
    float t  = (pax * abx + pay * aby) / dd;   // true IEEE divide
    t = fminf(fmaxf(t, 0.0f), 1.0f);
    float dx = pax - t * abx;
    float dy = pay - t * aby;
    return dx * dx + dy * dy;
}

// fast version with pre-staged reciprocal seed y == rcp2((ab.ab)+EPS)
__device__ __forceinline__ float seg_d2y(float pax, float pay, float abx, float aby, float y) {
#pragma clang fp contract(off)
    float dd = (abx * abx + aby * aby) + EPSF;   // ref op order
    float n  = pax * abx + pay * aby;
    float t  = fdivr(n, dd, y);
    t = fminf(fmaxf(t, 0.0f), 1.0f);
    float dx = pax - t * abx;
    float dy = pay - t * aby;
    return dx * dx + dy * dy;
}

__device__ __forceinline__ void ins4(u64& s0, u64& s1, u64& s2, u64& s3, u64 k) {
    bool c0 = k < s0, c1 = k < s1, c2 = k < s2, c3 = k < s3;
    s3 = c2 ? s2 : (c3 ? k : s3);
    s2 = c1 ? s1 : (c2 ? k : s2);
    s1 = c0 ? s0 : (c1 ? k : s1);
    s0 = c0 ? k  : s0;
}

// one survivor record -> candidate key (straight-line, no s3 dependence)
__device__ __forceinline__ u64 eval_rec(const float4* fd, float px, float py) {
#pragma clang fp contract(off)
    float4 r0 = fd[0];
    float4 r1 = fd[1];
    float4 r2 = fd[2];
    float4 r3 = fd[3];
    float a0x = r0.x, a0y = r0.y, a1x = r0.z, a1y = r0.w;
    float a2x = r1.x, a2y = r1.y, z0 = r1.z, z1 = r1.w;
    float z2 = r2.x, denom = r2.y, yd = r2.z;
    unsigned fi = __float_as_uint(r2.w);
    float ylA = r3.x, ylB = r3.y, ylC = r3.z;

    float e0x = a2x - a1x, e0y = a2y - a1y;   // a1->a2
    float e1x = a0x - a2x, e1y = a0y - a2y;   // a2->a0
    float e2x = a1x - a0x, e2y = a1y - a0y;   // a0->a1
    float p0x = px - a0x, p0y = py - a0y;
    float p1x = px - a1x, p1y = py - a1y;
    float p2x = px - a2x, p2y = py - a2y;
    float w0 = p1x * e0y - p1y * e0x;
    float w1 = p2x * e1y - p2y * e1x;
    float w2 = p0x * e2y - p0y * e2x;
    float b0 = fdivr(w0, denom, yd);
    float b1 = fdivr(w1, denom, yd);
    float b2 = fdivr(w2, denom, yd);
    float zpix = (b0 * z0 + b1 * z1) + b2 * z2;               // numpy order
    bool inside = fminf(b0, fminf(b1, b2)) >= 0.0f;           // no NaNs possible
    bool valid;
    if (__all(inside)) {
        valid = (zpix > EPSF);
    } else {
        float dA = seg_d2y(p0x, p0y, e2x, e2y, ylA);   // (p,a0,a1)
        float dB = seg_d2y(p1x, p1y, e0x, e0y, ylB);   // (p,a1,a2)
        float dC = seg_d2y(p2x, p2y, e1x, e1y, ylC);   // (p,a2,a0)
        float dmin = fminf(dA, fminf(dB, dC));
        valid = (inside | (dmin < BLURF)) & (zpix > EPSF);
    }
    return valid ? ((((u64)__float_as_uint(zpix)) << 32) | (u64)fi) : INVK;
}

// ---------------- kernel 1: per (tile, face-slice) partial top-4 ----------------
// Structure NOTE (measured r0-r12): the main loop stays straight-line with
// ALL top-4 gating at the BOTTOM (top-gates collapse cross-iteration ILP:
// r1/r3 +5%, r4 +37%). Fence-fusion 3.5x worse (r6); work-stealing 25% worse
// (r9, TLP halved); 2x unroll neutral (r10); per-iter far-filter neutral
// (r12). r11: survivors BIN-ORDERED by a provable per-tile z lower bound
// (zminT, affine corner min); between bins (8x max, NOT per-iter) an exact
// break fires once every lane's 4th key beats the remaining bins' bound.
__global__ __launch_bounds__(256) void raster_p1(
    const float* __restrict__ verts,   // (B, V, 3)
    const int*   __restrict__ faces,   // (F, 3)
    u64* __restrict__ ws,              // [512*S][4][64] partial keys
    int sh)                            // log2(slices)
{
#pragma clang fp contract(off)
    extern __shared__ __align__(16) float sFD[];   // [chunk][16] survivor records (64B)
    __shared__ u64 sK[2 * 4 * 64];     // merge rows (4 KB)
    __shared__ int sTot;
    __shared__ int binCnt[8];
    __shared__ int binCur[8];
    __shared__ int binStartS[9];

    const int S     = 1 << sh;
    const int chunk = NF >> sh;

    const int tid   = threadIdx.x;
    const int blk   = blockIdx.x;
    const int tile  = blk >> sh;
    const int slice = blk & (S - 1);
    const int b     = tile >> 8;
    const int trow  = (tile & 255) >> 4;
    const int tcol  = tile & 15;
    const float* vb = verts + b * NV * 3;
    const int fbase = slice * chunk;

    if (tid == 0) sTot = 0;
    if (tid < 8) binCnt[tid] = 0;

    // tile geometry (block-uniform)
    const float txmax = 1.0f - (2.0f * ((float)(tcol * 8)     + 0.5f)) / 128.0f;
    const float txmin = 1.0f - (2.0f * ((float)(tcol * 8 + 7) + 0.5f)) / 128.0f;
    const float tymax = 1.0f - (2.0f * ((float)(trow * 8)     + 0.5f)) / 128.0f;
    const float tymin = 1.0f - (2.0f * ((float)(trow * 8 + 7) + 0.5f)) / 128.0f;
    const float cx = 0.5f * (txmin + txmax);
    const float cy = 0.5f * (tymin + tymax);

    __syncthreads();   // counters visible

    if (chunk <= 256) {
        // ---- bin-ordered staging: each thread owns <=1 face, record lives in
        // registers across the count/prefix/scatter barriers (no recompute).
        bool surv = false;
        int bin = 0;
        float a0x=0, a0y=0, a1x=0, a1y=0, a2x=0, a2y=0, z0=0, z1=0, z2=0;
        float area=0, yd=0, ylA=0, ylB=0, ylC=0;
        int f = fbase + tid;
        if (tid < chunk) {
            int i0 = faces[3 * f + 0], i1 = faces[3 * f + 1], i2 = faces[3 * f + 2];
            a0x = vb[3 * i0]; a0y = vb[3 * i0 + 1]; z0 = vb[3 * i0 + 2];
            a1x = vb[3 * i1]; a1y = vb[3 * i1 + 1]; z1 = vb[3 * i1 + 2];
            a2x = vb[3 * i2]; a2y = vb[3 * i2 + 1]; z2 = vb[3 * i2 + 2];
            // numpy op order for area (exact-match)
            area = (a2x - a0x) * (a1y - a0y) - (a2y - a0y) * (a1x - a0x);
            surv = fabsf(area) > EPSF;
            float bxmin = fminf(a0x, fminf(a1x, a2x)) - 0.101f;
            float bxmax = fmaxf(a0x, fmaxf(a1x, a2x)) + 0.101f;
            float bymin = fminf(a0y, fminf(a1y, a2y)) - 0.101f;
            float bymax = fmaxf(a0y, fmaxf(a1y, a2y)) + 0.101f;
            surv &= !(bxmin > txmax || bxmax < txmin || bymin > tymax || bymax < tymin);
            // exact rect-vs-edge-line cull
            float s = (area >= 0.0f) ? 1.0f : -1.0f;
            float e0x = a2x - a1x, e0y = a2y - a1y;
            float e1x = a0x - a2x, e1y = a0y - a2y;
            float e2x = a1x - a0x, e2y = a1y - a0y;
            float w0 = s * ((cx - a1x) * e0y - (cy - a1y) * e0x) + HEXT * (fabsf(e0x) + fabsf(e0y));
            float w1 = s * ((cx - a2x) * e1y - (cy - a2y) * e1x) + HEXT * (fabsf(e1x) + fabsf(e1y));
            float w2 = s * ((cx - a0x) * e2y - (cy - a0y) * e2x) + HEXT * (fabsf(e2x) + fabsf(e2y));
            float l0 = e0x * e0x + e0y * e0y;
            float l1 = e1x * e1x + e1y * e1y;
            float l2 = e2x * e2x + e2y * e2y;
            surv &= !((w0 < 0.0f) & (w0 * w0 > CULL_D2 * l0));
            surv &= !((w1 < 0.0f) & (w1 * w1 > CULL_D2 * l1));
            surv &= !((w2 < 0.0f) & (w2 * w2 > CULL_D2 * l2));
            if (surv) {
                yd  = rcp2(area);          // survivor => denom == area
                ylA = rcp2(l2 + EPSF);     // seg a0->a1 (p0, e2) -> dA
                ylB = rcp2(l0 + EPSF);     // seg a1->a2 (p1, e0) -> dB
                ylC = rcp2(l1 + EPSF);     // seg a2->a0 (p2, e1) -> dC
                // z lower bound over the tile: z(x,y) is affine -> min at a
                // corner of the pixel-center rect. (*yd approx: covered by
                // ZSLACK; slivers excluded from skipping entirely.)
                float zmn = 1e30f;
                #pragma unroll
                for (int c = 0; c < 4; ++c) {
                    float X = (c & 1) ? txmax : txmin;
                    float Y = (c & 2) ? tymax : tymin;
                    float w0c = (X - a1x) * e0y - (Y - a1y) * e0x;
                    float w1c = (X - a2x) * e1y - (Y - a2y) * e1x;
                    float w2c = (X - a0x) * e2y - (Y - a0y) * e2x;
                    float zc = ((w0c * z0 + w1c * z1) + w2c * z2) * yd;
                    zmn = fminf(zmn, zc);
                }
                if (fabsf(area) < AREA_SLIVER) zmn = 0.0f;   // never skipped
                int bi = (int)floorf((zmn - 0.5f) * 4.0f);   // 8 bins of 0.25
                bin = bi < 0 ? 0 : (bi > 7 ? 7 : bi);
                atomicAdd(&binCnt[bin], 1);
            }
        }
        __syncthreads();
        if (tid == 0) {
            int run = 0;
            for (int bb = 0; bb < 8; ++bb) {
                binStartS[bb] = run;
                binCur[bb]    = run;
                run += binCnt[bb];
            }
            binStartS[8] = run;
        }
        __syncthreads();
        if (surv) {
            int pos = atomicAdd(&binCur[bin], 1);
            float4* fd = (float4*)&sFD[pos * 16];
            fd[0] = make_float4(a0x, a0y, a1x, a1y);
            fd[1] = make_float4(a2x, a2y, z0, z1);
            fd[2] = make_float4(z2, area, yd, __int_as_float(f));
            fd[3] = make_float4(ylA, ylB, ylC, 0.0f);
        }
        __syncthreads();
    } else {
        // fallback (sh<2): r8 staging, everything in bin 0, no z-skip
        for (int j = tid; j < chunk; j += 256) {
            int f = fbase + j;
            int i0 = faces[3 * f + 0], i1 = faces[3 * f + 1], i2 = faces[3 * f + 2];
            float a0x = vb[3 * i0], a0y = vb[3 * i0 + 1], z0 = vb[3 * i0 + 2];
            float a1x = vb[3 * i1], a1y = vb[3 * i1 + 1], z1 = vb[3 * i1 + 2];
            float a2x = vb[3 * i2], a2y = vb[3 * i2 + 1], z2 = vb[3 * i2 + 2];
            float area = (a2x - a0x) * (a1y - a0y) - (a2y - a0y) * (a1x - a0x);
            bool surv = fabsf(area) > EPSF;
            float bxmin = fminf(a0x, fminf(a1x, a2x)) - 0.101f;
            float bxmax = fmaxf(a0x, fmaxf(a1x, a2x)) + 0.101f;
            float bymin = fminf(a0y, fminf(a1y, a2y)) - 0.101f;
            float bymax = fmaxf(a0y, fmaxf(a1y, a2y)) + 0.101f;
            surv &= !(bxmin > txmax || bxmax < txmin || bymin > tymax || bymax < tymin);
            float s = (area >= 0.0f) ? 1.0f : -1.0f;
            float e0x = a2x - a1x, e0y = a2y - a1y;
            float e1x = a0x - a2x, e1y = a0y - a2y;
            float e2x = a1x - a0x, e2y = a1y - a0y;
            float w0 = s * ((cx - a1x) * e0y - (cy - a1y) * e0x) + HEXT * (fabsf(e0x) + fabsf(e0y));
            float w1 = s * ((cx - a2x) * e1y - (cy - a2y) * e1x) + HEXT * (fabsf(e1x) + fabsf(e1y));
            float w2 = s * ((cx - a0x) * e2y - (cy - a0y) * e2x) + HEXT * (fabsf(e2x) + fabsf(e2y));
            float l0 = e0x * e0x + e0y * e0y;
            float l1 = e1x * e1x + e1y * e1y;
            float l2 = e2x * e2x + e2y * e2y;
            surv &= !((w0 < 0.0f) & (w0 * w0 > CULL_D2 * l0));
            surv &= !((w1 < 0.0f) & (w1 * w1 > CULL_D2 * l1));
            surv &= !((w2 < 0.0f) & (w2 * w2 > CULL_D2 * l2));
            if (surv) {
                int pos = atomicAdd(&sTot, 1);
                float yd  = rcp2(area);
                float ylA = rcp2(l2 + EPSF);
                float ylB = rcp2(l0 + EPSF);
                float ylC = rcp2(l1 + EPSF);
                float4* fd = (float4*)&sFD[pos * 16];
                fd[0] = make_float4(a0x, a0y, a1x, a1y);
                fd[1] = make_float4(a2x, a2y, z0, z1);
                fd[2] = make_float4(z2, area, yd, __int_as_float(f));
                fd[3] = make_float4(ylA, ylB, ylC, 0.0f);
            }
        }
        __syncthreads();
        if (tid == 0) {
            binStartS[0] = 0;
            for (int bb = 1; bb <= 8; ++bb) binStartS[bb] = sTot;
        }
        __syncthreads();
    }

    const int wave = tid >> 6;
    const int lane = tid & 63;
    const int pr = lane >> 3, pc = lane & 7;          // 8x8 tile
    const int row = trow * 8 + pr, col = tcol * 8 + pc;
    const float px = 1.0f - (2.0f * ((float)col + 0.5f)) / 128.0f;
    const float py = 1.0f - (2.0f * ((float)row + 0.5f)) / 128.0f;

    // phase 1: bins in increasing-z order; within a bin the loop is the
    // r8-proven shape (straight-line, bottom gate). Break check reads s3 only
    // BETWEEN bins (<=8x) -- no per-iteration loop-carried dependency.
    u64 s0 = INVK, s1 = INVK, s2 = INVK, s3 = INVK;
    for (int bb = 0; bb < 8; ++bb) {
        if (bb > 0) {
            float bz = 0.5f + 0.25f * (float)bb - ZSLACK;
            u64 bk = ((u64)__float_as_uint(bz)) << 32;
            if (!__any(s3 > bk)) break;   // exact: future keys > bk >= all s3
        }
        const int jend = binStartS[bb + 1];
        for (int j = binStartS[bb] + wave; j < jend; j += 4) {
            u64 k = eval_rec((const float4*)&sFD[j * 16], px, py);
            if (__any(k < s3)) ins4(s0, s1, s2, s3, k);
        }
    }

    // cross-wave merge: 4 waves -> wave 0
    if (wave >= 2) {
        int r = wave - 2;
        sK[(r * 4 + 0) * 64 + lane] = s0;
        sK[(r * 4 + 1) * 64 + lane] = s1;
        sK[(r * 4 + 2) * 64 + lane] = s2;
        sK[(r * 4 + 3) * 64 + lane] = s3;
    }
    __syncthreads();
    if (wave < 2) {
        ins4(s0, s1, s2, s3, sK[(wave * 4 + 0) * 64 + lane]);
        ins4(s0, s1, s2, s3, sK[(wave * 4 + 1) * 64 + lane]);
        ins4(s0, s1, s2, s3, sK[(wave * 4 + 2) * 64 + lane]);
        ins4(s0, s1, s2, s3, sK[(wave * 4 + 3) * 64 + lane]);
    }
    __syncthreads();
    if (wave == 1) {
        sK[0 * 64 + lane] = s0;
        sK[1 * 64 + lane] = s1;
        sK[2 * 64 + lane] = s2;
        sK[3 * 64 + lane] = s3;
    }
    __syncthreads();
    if (wave == 0) {
        ins4(s0, s1, s2, s3, sK[0 * 64 + lane]);
        ins4(s0, s1, s2, s3, sK[1 * 64 + lane]);
        ins4(s0, s1, s2, s3, sK[2 * 64 + lane]);
        ins4(s0, s1, s2, s3, sK[3 * 64 + lane]);
        u64* wrow = ws + (size_t)blk * 256;
        wrow[0 * 64 + lane] = s0;
        wrow[1 * 64 + lane] = s1;
        wrow[2 * 64 + lane] = s2;
        wrow[3 * 64 + lane] = s3;
    }
}

// ---------------- kernel 2: merge slices + exact epilogue ----------------
__global__ __launch_bounds__(256) void raster_p2(
    const float* __restrict__ verts,
    const int*   __restrict__ faces,
    const u64* __restrict__ ws,
    int sh,
    float* __restrict__ out0, float* __restrict__ out1,
    float* __restrict__ out2, float* __restrict__ out3)
{
#pragma clang fp contract(off)
    __shared__ u64 sK[4 * 64];
    const int S    = 1 << sh;
    const int tid  = threadIdx.x;
    const int tile = blockIdx.x;
    const int b    = tile >> 8;
    const int trow = (tile & 255) >> 4;
    const int tcol = tile & 15;
    const float* vb = verts + b * NV * 3;

    if (tid < 64) {
        u64 s0 = INVK, s1 = INVK, s2 = INVK, s3 = INVK;
        const u64* base = ws + (size_t)tile * S * 256;
        for (int s = 0; s < S; ++s) {
            ins4(s0, s1, s2, s3, base[s * 256 + 0 * 64 + tid]);
            ins4(s0, s1, s2, s3, base[s * 256 + 1 * 64 + tid]);
            ins4(s0, s1, s2, s3, base[s * 256 + 2 * 64 + tid]);
            ins4(s0, s1, s2, s3, base[s * 256 + 3 * 64 + tid]);
        }
        sK[0 * 64 + tid] = s0;
        sK[1 * 64 + tid] = s1;
        sK[2 * 64 + tid] = s2;
        sK[3 * 64 + tid] = s3;
    }
    __syncthreads();

    int pix = tid >> 2, k = tid & 3;
    u64 key = sK[k * 64 + pix];
    int prow = pix >> 3, pcol = pix & 7;
    int grow = trow * 8 + prow, gcol = tcol * 8 + pcol;
    int p = (b * IMG + grow) * IMG + gcol;
    float qx = 1.0f - (2.0f * ((float)gcol + 0.5f)) / 128.0f;
    float qy = 1.0f - (2.0f * ((float)grow + 0.5f)) / 128.0f;
    float o0 = -1.0f, o1 = -1.0f, ob0 = -1.0f, ob1 = -1.0f, ob2 = -1.0f, o3 = -1.0f;
    if ((unsigned)(key >> 32) != 0x7f800000u) {
        int fi = (int)(unsigned)(key & 0xffffffffu);
        int i0 = faces[3 * fi + 0], i1 = faces[3 * fi + 1], i2 = faces[3 * fi + 2];
        float a0x = vb[3 * i0], a0y = vb[3 * i0 + 1], z0 = vb[3 * i0 + 2];
        float a1x = vb[3 * i1], a1y = vb[3 * i1 + 1], z1 = vb[3 * i1 + 2];
        float a2x = vb[3 * i2], a2y = vb[3 * i2 + 1], z2 = vb[3 * i2 + 2];
        float area = (a2x - a0x) * (a1y - a0y) - (a2y - a0y) * (a1x - a0x);
        float aab  = fabsf(area);
        float denom = (aab > EPSF) ? area : (area >= 0.0f ? EPSF : -EPSF);
        float e0x = a2x - a1x, e0y = a2y - a1y;
        float e1x = a0x - a2x, e1y = a0y - a2y;
        float e2x = a1x - a0x, e2y = a1y - a0y;
        float p0x = qx - a0x, p0y = qy - a0y;
        float p1x = qx - a1x, p1y = qy - a1y;
        float p2x = qx - a2x, p2y = qy - a2y;
        float w0 = p1x * e0y - p1y * e0x;
        float w1 = p2x * e1y - p2y * e1x;
        float w2 = p0x * e2y - p0y * e2x;
        float b0 = w0 / denom, b1 = w1 / denom, b2 = w2 / denom;   // true IEEE
        float zpix = (b0 * z0 + b1 * z1) + b2 * z2;
        bool inside = (b0 >= 0.0f) & (b1 >= 0.0f) & (b2 >= 0.0f);
        float dA = seg_d2(p0x, p0y, e2x, e2y);
        float dB = seg_d2(p1x, p1y, e0x, e0y);
        float dC = seg_d2(p2x, p2y, e1x, e1y);
        float dmin = fminf(dA, fminf(dB, dC));
        o0 = (float)fi;
        o1 = zpix;
        ob0 = b0; ob1 = b1; ob2 = b2;
        o3 = inside ? -dmin : dmin;
    }
    int o = p * KF + k;
    out0[o] = o0;
    out1[o] = o1;
    out2[o * 3 + 0] = ob0;
    out2[o * 3 + 1] = ob1;
    out2[o * 3 + 2] = ob2;
    out3[o] = o3;
}

extern "C" void kernel_launch(void* const* d_in, const int* in_sizes, int n_in,
                              void* d_out, int out_size, void* d_ws, size_t ws_size,
                              hipStream_t stream) {
    const float* verts = (const float*)d_in[0];
    const int*   faces = (const int*)d_in[1];
    float* out = (float*)d_out;
    const int n0 = NB * IMG * IMG * KF;   // 131072 per (B,H,W,K) output

    const size_t per_slice = 512ull * 256 * sizeof(u64);   // 1 MB
    // Measured: sh=3 worse (r1), 8-wave worse (r3), top-gated loops worse
    // (r1/r3/r4), fence-fused kernel 3.5x worse (r6), work-stealing 25% worse
    // (r9), 2x unroll neutral (r10), per-iter far-filter neutral (r12).
    // FINAL (measured best, 79.7 us): sh=2 / bottom-gated loop + staged seeds
    // + compacted float4 records (r8) + z-binned exact early break (r11).
    int sh;
    if      (ws_size >= 4 * per_slice) sh = 2;   // 4 slices
    else if (ws_size >= 2 * per_slice) sh = 1;   // 2 slices
    else                               sh = 0;   // 1 slice
    const int S = 1 << sh;
    const int chunk = NF >> sh;
    const size_t dyn = (size_t)chunk * 16 * sizeof(float);

    raster_p1<<<dim3(512 * S), dim3(256), dyn, stream>>>(verts, faces, (u64*)d_ws, sh);
    raster_p2<<<dim3(512), dim3(256), 0, stream>>>(verts, faces, (const u64*)d_ws, sh,
        out,                 // pix_to_face
        out + n0,            // zbuf
        out + 2 * n0,        // bary
        out + 5 * n0);       // dsign
}